// Round 2
// baseline (3736.769 us; speedup 1.0000x reference)
//
#include <hip/hip_runtime.h>

#define TILE 16
#define KOUT 8
#define CCH 4

// ---------------- conv 3x3 SAME ----------------
// Optional: nearest-2x-upsampled input (upsample), relu, accumulate-into-out
// (accum: out[i] = relu?(out[i] + conv) — in-place safe, thread owns element).
// Weight tensor may cover more input channels than this pass uses:
//   w index = ((coBase+k)*Cw + c_off + ci)*9 + j
__global__ __launch_bounds__(256) void conv3x3_k(
    const float* __restrict__ in, int Cin,
    const float* __restrict__ w, int Cw, int c_off,
    const float* __restrict__ bias,
    float* __restrict__ out, int Cout, int H, int W,
    int upsample, int relu, int accum)
{
    __shared__ float s_in[CCH][TILE + 2][TILE + 2];
    const int tx = threadIdx.x, ty = threadIdx.y;
    const int tid = ty * TILE + tx;
    const int groups = Cout / KOUT;
    const int b = blockIdx.z / groups;
    const int coBase = (blockIdx.z % groups) * KOUT;
    const int bx = blockIdx.x * TILE, by = blockIdx.y * TILE;
    const int sH = upsample ? (H >> 1) : H;
    const int sW = upsample ? (W >> 1) : W;

    float acc[KOUT];
#pragma unroll
    for (int k = 0; k < KOUT; k++) acc[k] = 0.f;

    for (int c0 = 0; c0 < Cin; c0 += CCH) {
        const int nc = min(CCH, Cin - c0);
        // stage input tile for nc channels
        for (int i = tid; i < nc * (TILE + 2) * (TILE + 2); i += 256) {
            const int cc = i / ((TILE + 2) * (TILE + 2));
            const int r = i % ((TILE + 2) * (TILE + 2));
            const int ly = r / (TILE + 2), lx = r % (TILE + 2);
            const int gy = by + ly - 1, gx = bx + lx - 1;
            float v = 0.f;
            if (gy >= 0 && gy < H && gx >= 0 && gx < W) {
                const float* src = in + (size_t)(b * Cin + c0 + cc) * (size_t)(sH * sW);
                v = upsample ? src[(gy >> 1) * sW + (gx >> 1)] : src[gy * W + gx];
            }
            ((float*)s_in)[i] = v;  // [cc][18][18] linear in i
        }
        __syncthreads();
        for (int cc = 0; cc < nc; ++cc) {
            float v[9];
#pragma unroll
            for (int dh = 0; dh < 3; dh++)
#pragma unroll
                for (int dw = 0; dw < 3; dw++)
                    v[dh * 3 + dw] = s_in[cc][ty + dh][tx + dw];
            // wave-uniform weight addresses -> scalar loads
            const float* wp = w + ((size_t)coBase * Cw + (size_t)(c_off + c0 + cc)) * 9;
#pragma unroll
            for (int k = 0; k < KOUT; k++) {
                const float* wk = wp + (size_t)k * Cw * 9;
                float a = acc[k];
#pragma unroll
                for (int j = 0; j < 9; j++) a = fmaf(v[j], wk[j], a);
                acc[k] = a;
            }
        }
        __syncthreads();
    }
    const int h = by + ty, ww = bx + tx;
#pragma unroll
    for (int k = 0; k < KOUT; k++) {
        size_t oi = ((size_t)(b * Cout + coBase + k) * H + h) * W + ww;
        float val = acc[k];
        if (bias) val += bias[coBase + k];
        if (accum) val += out[oi];
        if (relu) val = fmaxf(val, 0.f);
        out[oi] = val;
    }
}

// ---------------- 2x2 max pool stride 2 ----------------
__global__ void maxpool_k(const float* __restrict__ in, float* __restrict__ out,
                          int H, int W, int total)
{
    int idx = blockIdx.x * 256 + threadIdx.x;
    if (idx >= total) return;
    const int Wo = W >> 1, Ho = H >> 1;
    int ow = idx % Wo;
    int t = idx / Wo;
    int oh = t % Ho;
    t /= Ho;  // plane index b*C+c
    const float* p = in + (size_t)t * H * W + (size_t)(oh * 2) * W + ow * 2;
    out[idx] = fmaxf(fmaxf(p[0], p[1]), fmaxf(p[W], p[W + 1]));
}

// ---------------- 1x1 conv 32->32, no relu ----------------
__global__ __launch_bounds__(256) void conv1x1_k(
    const float* __restrict__ in, const float* __restrict__ w,
    const float* __restrict__ bias, float* __restrict__ out, int HW)
{
    __shared__ float sw[32 * 32];
    __shared__ float sb[32];
    const int tid = threadIdx.x;
    for (int i = tid; i < 1024; i += 256) sw[i] = w[i];
    if (tid < 32) sb[tid] = bias[tid];
    __syncthreads();
    const size_t p = (size_t)blockIdx.x * 256 + tid;  // over B*HW
    const int b = (int)(p / HW);
    const int pix = (int)(p % HW);
    const float* ip = in + (size_t)b * 32 * HW + pix;
    float x[32];
#pragma unroll
    for (int ci = 0; ci < 32; ci++) x[ci] = ip[(size_t)ci * HW];
    float* op = out + (size_t)b * 32 * HW + pix;
#pragma unroll
    for (int co = 0; co < 32; co++) {
        float a = sb[co];
#pragma unroll
        for (int ci = 0; ci < 32; ci++) a = fmaf(x[ci], sw[co * 32 + ci], a);
        op[(size_t)co * HW] = a;
    }
}

// ---------------- integral image: row inclusive scan ----------------
__global__ __launch_bounds__(256) void rowscan_k(const float* __restrict__ f,
                                                 float* __restrict__ ii)
{
    __shared__ float s[256];
    const int row = blockIdx.x;  // bc*256 + y
    const int tid = threadIdx.x;
    const int bc = row >> 8, y = row & 255;
    s[tid] = f[(size_t)row * 256 + tid];
    __syncthreads();
#pragma unroll
    for (int off = 1; off < 256; off <<= 1) {
        float t = (tid >= off) ? s[tid - off] : 0.f;
        __syncthreads();
        s[tid] += t;
        __syncthreads();
    }
    float* prow = ii + (size_t)bc * 66049 + (size_t)(y + 1) * 257;
    prow[tid + 1] = s[tid];
    if (tid == 0) prow[0] = 0.f;
}

__global__ void zrow_k(float* __restrict__ ii, int total)
{
    int i = blockIdx.x * 256 + threadIdx.x;
    if (i < total) {
        int bc = i / 257, x = i % 257;
        ii[(size_t)bc * 66049 + x] = 0.f;
    }
}

// ---------------- integral image: column serial scan ----------------
__global__ __launch_bounds__(256) void colscan_k(float* __restrict__ ii)
{
    float* plane = ii + (size_t)blockIdx.x * 66049;
    const int x = threadIdx.x + 1;
    float acc = 0.f;
    for (int y = 1; y <= 256; ++y) {
        float* p = plane + (size_t)y * 257 + x;
        acc += *p;
        *p = acc;
    }
}

// ---------------- fused adaptive ROI pool (7x7 via integral image) + FC ----------------
__global__ __launch_bounds__(512) void roifc_k(
    const float* __restrict__ ii, const int* __restrict__ rois,
    const float* __restrict__ fcw, const float* __restrict__ fcb,
    float* __restrict__ out)
{
    __shared__ float sp[49];
    const int n = blockIdx.x, b = blockIdx.y;
    const int tid = threadIdx.x;
    if (tid < 49) {
        const int i = tid / 7, j = tid % 7;
        int x1, y1, x2, y2, c;
        if (n < 32) {
            x1 = 0; y1 = 0; x2 = 256; y2 = 256; c = n;
        } else {
            int r = (n - 32) >> 5;
            c = (n - 32) & 31;
            x1 = rois[r * 4 + 0]; y1 = rois[r * 4 + 1];
            x2 = rois[r * 4 + 2]; y2 = rois[r * 4 + 3];
        }
        const int h = y2 - y1, w = x2 - x1;
        const int sy = y1 + (i * h) / 7, ey = y1 + ((i + 1) * h + 6) / 7;
        const int sx = x1 + (j * w) / 7, ex = x1 + ((j + 1) * w + 6) / 7;
        const float* pl = ii + (size_t)(b * 32 + c) * 66049;
        float s = pl[ey * 257 + ex] - pl[sy * 257 + ex] - pl[ey * 257 + sx] + pl[sy * 257 + sx];
        sp[tid] = s / (float)((ey - sy) * (ex - sx));
    }
    __syncthreads();
    float a = fcb[tid];
    const float* wr = fcw + (size_t)tid * 49;
#pragma unroll
    for (int k = 0; k < 49; k++) a = fmaf(sp[k], wr[k], a);
    out[((size_t)(b * 1056) + n) * 512 + tid] = a;
}

extern "C" void kernel_launch(void* const* d_in, const int* in_sizes, int n_in,
                              void* d_out, int out_size, void* d_ws, size_t ws_size,
                              hipStream_t stream)
{
    const float* x    = (const float*)d_in[0];
    const int*   rois = (const int*)d_in[1];
    const float* e1w1 = (const float*)d_in[2];
    const float* e1b1 = (const float*)d_in[3];
    const float* e1w2 = (const float*)d_in[4];
    const float* e1b2 = (const float*)d_in[5];
    const float* e2w1 = (const float*)d_in[6];
    const float* e2b1 = (const float*)d_in[7];
    const float* e2w2 = (const float*)d_in[8];
    const float* e2b2 = (const float*)d_in[9];
    const float* bw1  = (const float*)d_in[10];
    const float* bb1  = (const float*)d_in[11];
    const float* bw2  = (const float*)d_in[12];
    const float* bb2  = (const float*)d_in[13];
    const float* u2w  = (const float*)d_in[14];
    const float* u2b  = (const float*)d_in[15];
    const float* d2w1 = (const float*)d_in[16];
    const float* d2b1 = (const float*)d_in[17];
    const float* d2w2 = (const float*)d_in[18];
    const float* d2b2 = (const float*)d_in[19];
    const float* u1w  = (const float*)d_in[20];
    const float* u1b  = (const float*)d_in[21];
    const float* d1w1 = (const float*)d_in[22];
    const float* d1b1 = (const float*)d_in[23];
    const float* d1w2 = (const float*)d_in[24];
    const float* d1b2 = (const float*)d_in[25];
    const float* fw   = (const float*)d_in[26];
    const float* fb   = (const float*)d_in[27];
    const float* fcw  = (const float*)d_in[28];
    const float* fcb  = (const float*)d_in[29];

    // ---- workspace layout: 5 slots, 50,331,648 floats = 192 MB total ----
    float* ws = (float*)d_ws;
    float* A = ws + 0;          // 64 MB: e1a, e2a, b2, t2/d2a, t1/d1a, f
    float* Bs = ws + 16777216;  // 64 MB: e1, u1, ii(start)
    float* D = ws + 33554432;   // 32 MB: e2, d2, d1(start), ii(tail)
    float* C = ws + 41943040;   // 16 MB: p1, p2, u2(start), d1(mid)
    float* E = ws + 46137344;   // 16 MB: b1, u2(tail), d1(tail)
    float* u2buf = C;           // C+E contiguous 32 MB
    float* d1buf = D;           // D+C+E contiguous 64 MB
    float* ii    = Bs;          // 16,908,544 floats: B + dead sliver of D

    auto cv = [&](const float* i, int Cin, const float* wgt, int Cw, int coff,
                  const float* bs, float* o, int Cout, int H, int W,
                  int up, int relu, int accum) {
        dim3 g(W / TILE, H / TILE, 8 * (Cout / KOUT));
        hipLaunchKernelGGL(conv3x3_k, g, dim3(TILE, TILE), 0, stream,
                           i, Cin, wgt, Cw, coff, bs, o, Cout, H, W, up, relu, accum);
    };

    // encoder
    cv(x, 3, e1w1, 3, 0, e1b1, A, 32, 256, 256, 0, 1, 0);            // e1a -> A
    cv(A, 32, e1w2, 32, 0, e1b2, Bs, 32, 256, 256, 0, 1, 0);         // e1  -> B
    {
        int N = 8 * 32 * 128 * 128;
        hipLaunchKernelGGL(maxpool_k, dim3((N + 255) / 256), dim3(256), 0, stream, Bs, C, 256, 256, N);
    }                                                                 // p1 -> C
    cv(C, 32, e2w1, 32, 0, e2b1, A, 64, 128, 128, 0, 1, 0);          // e2a -> A
    cv(A, 64, e2w2, 64, 0, e2b2, D, 64, 128, 128, 0, 1, 0);          // e2  -> D
    {
        int N = 8 * 64 * 64 * 64;
        hipLaunchKernelGGL(maxpool_k, dim3((N + 255) / 256), dim3(256), 0, stream, D, C, 128, 128, N);
    }                                                                 // p2 -> C
    // bottleneck
    cv(C, 64, bw1, 64, 0, bb1, E, 128, 64, 64, 0, 1, 0);             // b1 -> E
    cv(E, 128, bw2, 128, 0, bb2, A, 128, 64, 64, 0, 1, 0);           // b2 -> A
    // decoder level 2 (concat conv split into 2 linear passes)
    cv(A, 128, u2w, 128, 0, u2b, u2buf, 64, 128, 128, 1, 1, 0);      // u2 -> C+E
    cv(D, 64, d2w1, 128, 64, d2b1, A, 64, 128, 128, 0, 0, 0);        // t2 = W[:,64:]*e2 + b -> A
    cv(u2buf, 64, d2w1, 128, 0, nullptr, A, 64, 128, 128, 0, 1, 1);  // d2a = relu(t2 + W[:,:64]*u2)
    cv(A, 64, d2w2, 64, 0, d2b2, D, 64, 128, 128, 0, 1, 0);          // d2 -> D
    // decoder level 1
    cv(Bs, 32, d1w1, 64, 32, d1b1, A, 32, 256, 256, 0, 0, 0);        // t1 = W[:,32:]*e1 + b -> A
    cv(D, 64, u1w, 64, 0, u1b, Bs, 32, 256, 256, 1, 1, 0);           // u1 -> B (e1 dead)
    cv(Bs, 32, d1w1, 64, 0, nullptr, A, 32, 256, 256, 0, 1, 1);      // d1a = relu(t1 + W[:,:32]*u1)
    cv(A, 32, d1w2, 32, 0, d1b2, d1buf, 32, 256, 256, 0, 1, 0);      // d1 -> D+C+E
    // final 1x1
    hipLaunchKernelGGL(conv1x1_k, dim3(8 * 65536 / 256), dim3(256), 0, stream,
                       d1buf, fw, fb, A, 65536);                      // f -> A
    // integral image (into B + dead sliver of D)
    hipLaunchKernelGGL(rowscan_k, dim3(8 * 32 * 256), dim3(256), 0, stream, A, ii);
    hipLaunchKernelGGL(zrow_k, dim3((8 * 32 * 257 + 255) / 256), dim3(256), 0, stream, ii, 8 * 32 * 257);
    hipLaunchKernelGGL(colscan_k, dim3(8 * 32), dim3(256), 0, stream, ii);
    // fused ROI adaptive pool + FC
    hipLaunchKernelGGL(roifc_k, dim3(1056, 8), dim3(512), 0, stream,
                       ii, rois, fcw, fcb, (float*)d_out);
}

// Round 3
// 667.443 us; speedup vs baseline: 5.5986x; 5.5986x over previous
//
#include <hip/hip_runtime.h>

typedef _Float16 half8 __attribute__((ext_vector_type(8)));
typedef float f32x4 __attribute__((ext_vector_type(4)));

__device__ __forceinline__ unsigned short f2h(float f) {
    _Float16 h = (_Float16)f;
    return __builtin_bit_cast(unsigned short, h);
}
__device__ __forceinline__ float h2f(unsigned short u) {
    return (float)__builtin_bit_cast(_Float16, u);
}

// ---- weight transform: OIHW fp32 -> [ck][pos][oct(ci/8)][co][ci&7] fp16 ----
__global__ void wprep_k(const float* __restrict__ src, unsigned short* __restrict__ dst,
                        int Cout, int Cin, int total)
{
    int t = blockIdx.x * 256 + threadIdx.x;
    if (t >= total) return;
    int j = t & 7; int r = t >> 3;
    int co = r % Cout; r /= Cout;
    int oct = r & 3; r >>= 2;
    int pos = r % 9; int ck = r / 9;
    int ci = ck * 32 + oct * 8 + j;
    dst[t] = f2h(src[((size_t)co * Cin + ci) * 9 + pos]);
}

// ---- MFMA conv3x3 SAME, NHWC fp16, fp32 accum ----
// Block: 256 thr = 4 waves; tile = TH rows x W cols = 256 px; BM out-channels.
// K-loop: chunks of 32 input channels; 9 taps as accumulated GEMMs.
// LDS input: [oct(4)][TH+2][W+2] granules of 16B (8 ch); weights [pos][oct][co][8].
template<int BM>
__global__ __launch_bounds__(256) void convm_k(
    const uint4* __restrict__ in1, int C1g,
    const uint4* __restrict__ in2, int C2g,
    const uint4* __restrict__ wt,
    const float* __restrict__ bias,
    unsigned short* __restrict__ out,
    int Cout, int H, int lw, int TH, int upsample, int relu)
{
    constexpr int NM = BM / 16;
    __shared__ uint4 smem[4386];  // input planes + weight tile (<= 70,176 B)
    const int W = 1 << lw;
    const int WC = W + 2, HR = TH + 2;
    const int IN_GR = 4 * HR * WC;
    const int tid = threadIdx.x;
    const int lane = tid & 63, wv = tid >> 6;
    const int ng = Cout / BM;
    const int b = blockIdx.z / ng, cg = blockIdx.z % ng;
    const int y0 = blockIdx.y * TH;
    const int NCK = (C1g + C2g) / 4;

    f32x4 acc[NM][4];
#pragma unroll
    for (int m = 0; m < NM; ++m)
#pragma unroll
        for (int n = 0; n < 4; ++n) acc[m][n] = (f32x4){0.f, 0.f, 0.f, 0.f};

    const int l15 = lane & 15, l4 = lane >> 4;
    const int laneB = l4 * HR * WC + l15;  // k-octet plane + pixel offset
    const int laneA = l4 * BM + l15;       // k-octet + out-channel

    for (int ck = 0; ck < NCK; ++ck) {
        if (ck) __syncthreads();
        // stage input chunk (32 ch) with halo; concat source select per chunk
        {
            const uint4* src; int cg0, srcCg;
            if (ck * 4 < C1g) { src = in1; cg0 = ck * 4; srcCg = C1g; }
            else              { src = in2; cg0 = ck * 4 - C1g; srcCg = C2g; }
            const int sH = upsample ? (H >> 1) : H;
            const int sW = upsample ? (W >> 1) : W;
            for (int i = tid; i < IN_GR; i += 256) {
                int oct = i / (HR * WC);
                int rem = i - oct * (HR * WC);
                int row = rem / WC;
                int col = rem - row * WC;
                int gy = y0 + row - 1, gx = col - 1;
                if (upsample) { gy >>= 1; gx >>= 1; }
                uint4 v = make_uint4(0u, 0u, 0u, 0u);
                if ((unsigned)gy < (unsigned)sH && (unsigned)gx < (unsigned)sW)
                    v = src[(((size_t)b * sH + gy) * sW + gx) * srcCg + cg0 + oct];
                smem[i] = v;
            }
        }
        // stage weight chunk: 9 pos x 4 oct x BM co granules
        {
            const uint4* wck = wt + (size_t)ck * 36 * Cout;
            for (int i = tid; i < 36 * BM; i += 256) {
                int seg = i / BM, col = i - seg * BM;
                smem[IN_GR + i] = wck[seg * Cout + cg * BM + col];
            }
        }
        __syncthreads();
        const half8* sB = (const half8*)smem;
        const half8* sA = (const half8*)(smem + IN_GR);
#pragma unroll
        for (int pos = 0; pos < 9; ++pos) {
            const int dr = pos / 3, dc = pos - dr * 3;
            half8 af[NM], bfr[4];
#pragma unroll
            for (int m = 0; m < NM; ++m)
                af[m] = sA[pos * 4 * BM + m * 16 + laneA];
#pragma unroll
            for (int n = 0; n < 4; ++n) {
                int pb = wv * 64 + n * 16;
                int rn = (pb >> lw) + dr;
                int xn = (pb & (W - 1)) + dc;
                bfr[n] = sB[rn * WC + xn + laneB];
            }
#pragma unroll
            for (int m = 0; m < NM; ++m)
#pragma unroll
                for (int n = 0; n < 4; ++n)
                    acc[m][n] = __builtin_amdgcn_mfma_f32_16x16x32_f16(af[m], bfr[n], acc[m][n], 0, 0, 0);
        }
    }

    // epilogue: bias + relu, pack fp16, NHWC store (4 consecutive co per lane)
#pragma unroll
    for (int m = 0; m < NM; ++m) {
        const int co0 = cg * BM + m * 16 + l4 * 4;
        const float4 bs = *(const float4*)(bias + co0);
#pragma unroll
        for (int n = 0; n < 4; ++n) {
            int pix = wv * 64 + n * 16 + l15;
            int y = y0 + (pix >> lw), x = pix & (W - 1);
            float v0 = acc[m][n][0] + bs.x;
            float v1 = acc[m][n][1] + bs.y;
            float v2 = acc[m][n][2] + bs.z;
            float v3 = acc[m][n][3] + bs.w;
            if (relu) {
                v0 = fmaxf(v0, 0.f); v1 = fmaxf(v1, 0.f);
                v2 = fmaxf(v2, 0.f); v3 = fmaxf(v3, 0.f);
            }
            uint2 pk;
            pk.x = (unsigned)f2h(v0) | ((unsigned)f2h(v1) << 16);
            pk.y = (unsigned)f2h(v2) | ((unsigned)f2h(v3) << 16);
            *(uint2*)(out + (((size_t)b * H + y) * W + x) * Cout + co0) = pk;
        }
    }
}

// ---- first conv 3->32, fp32 direct, NCHW fp32 in -> NHWC fp16 out ----
__global__ __launch_bounds__(256) void conv0_k(
    const float* __restrict__ in, const float* __restrict__ w,
    const float* __restrict__ bias, unsigned short* __restrict__ out)
{
    __shared__ float s_in[3][18][18];
    const int tx = threadIdx.x, ty = threadIdx.y;
    const int tid = ty * 16 + tx;
    const int b = blockIdx.z >> 2;
    const int coBase = (blockIdx.z & 3) * 8;
    const int bx = blockIdx.x * 16, by = blockIdx.y * 16;

    for (int i = tid; i < 3 * 18 * 18; i += 256) {
        int cc = i / 324, r = i % 324;
        int ly = r / 18, lx = r % 18;
        int gy = by + ly - 1, gx = bx + lx - 1;
        float v = 0.f;
        if ((unsigned)gy < 256u && (unsigned)gx < 256u)
            v = in[(((size_t)(b * 3 + cc)) << 16) + (gy << 8) + gx];
        ((float*)s_in)[i] = v;
    }
    __syncthreads();
    float acc[8];
#pragma unroll
    for (int k = 0; k < 8; ++k) acc[k] = 0.f;
    for (int cc = 0; cc < 3; ++cc) {
        float v[9];
#pragma unroll
        for (int dh = 0; dh < 3; ++dh)
#pragma unroll
            for (int dw = 0; dw < 3; ++dw)
                v[dh * 3 + dw] = s_in[cc][ty + dh][tx + dw];
        const float* wp = w + ((size_t)coBase * 3 + cc) * 9;
#pragma unroll
        for (int k = 0; k < 8; ++k) {
            const float* wk = wp + (size_t)k * 27;
            float a = acc[k];
#pragma unroll
            for (int j = 0; j < 9; ++j) a = fmaf(v[j], wk[j], a);
            acc[k] = a;
        }
    }
    const int h = by + ty, ww = bx + tx;
    unsigned short* op = out + (((size_t)(b * 256 + h)) * 256 + ww) * 32 + coBase;
#pragma unroll
    for (int k = 0; k < 8; ++k)
        op[k] = f2h(fmaxf(acc[k] + bias[coBase + k], 0.f));
}

// ---- 2x2 maxpool stride 2, NHWC fp16, 8 ch per thread ----
__global__ void poolh_k(const uint4* __restrict__ in, uint4* __restrict__ out,
                        int Ho, int Wo, int C8, int total)
{
    int i = blockIdx.x * 256 + threadIdx.x;
    if (i >= total) return;
    int oct = i % C8; int p = i / C8;
    int x = p % Wo; p /= Wo;
    int y = p % Ho; int b = p / Ho;
    const int H = Ho * 2, W = Wo * 2;
    size_t g = (((size_t)b * H + 2 * y) * W + 2 * x) * C8 + oct;
    uint4 v00 = in[g], v01 = in[g + C8];
    uint4 v10 = in[g + (size_t)W * C8], v11 = in[g + (size_t)W * C8 + C8];
    const unsigned short* a0 = (const unsigned short*)&v00;
    const unsigned short* a1 = (const unsigned short*)&v01;
    const unsigned short* a2 = (const unsigned short*)&v10;
    const unsigned short* a3 = (const unsigned short*)&v11;
    uint4 res; unsigned short* rp = (unsigned short*)&res;
#pragma unroll
    for (int j = 0; j < 8; ++j)
        rp[j] = f2h(fmaxf(fmaxf(h2f(a0[j]), h2f(a1[j])), fmaxf(h2f(a2[j]), h2f(a3[j]))));
    out[(((size_t)b * Ho + y) * Wo + x) * C8 + oct] = res;
}

// ---- 1x1 conv 32->32, NHWC fp16 in -> NCHW fp32 out (for integral image) ----
__global__ __launch_bounds__(256) void conv1x1h_k(
    const uint4* __restrict__ in, const float* __restrict__ w,
    const float* __restrict__ bias, float* __restrict__ out)
{
    __shared__ float sw[1024];
    __shared__ float sb[32];
    const int tid = threadIdx.x;
    for (int i = tid; i < 1024; i += 256) sw[i] = w[i];
    if (tid < 32) sb[tid] = bias[tid];
    __syncthreads();
    const size_t p = (size_t)blockIdx.x * 256 + tid;  // over 8*65536 pixels
    float xv[32];
    const uint4* ip = in + p * 4;
#pragma unroll
    for (int q = 0; q < 4; ++q) {
        uint4 g = ip[q];
        const unsigned short* gs = (const unsigned short*)&g;
#pragma unroll
        for (int j = 0; j < 8; ++j) xv[q * 8 + j] = h2f(gs[j]);
    }
    const int b = (int)(p >> 16);
    const int pix = (int)(p & 65535);
    float* op = out + (((size_t)b * 32) << 16) + pix;
#pragma unroll
    for (int co = 0; co < 32; ++co) {
        float a = sb[co];
#pragma unroll
        for (int ci = 0; ci < 32; ++ci) a = fmaf(xv[ci], sw[co * 32 + ci], a);
        op[(size_t)co << 16] = a;
    }
}

// ---- integral image: row inclusive scan ----
__global__ __launch_bounds__(256) void rowscan_k(const float* __restrict__ f,
                                                 float* __restrict__ ii)
{
    __shared__ float s[256];
    const int row = blockIdx.x;  // bc*256 + y
    const int tid = threadIdx.x;
    const int bc = row >> 8, y = row & 255;
    s[tid] = f[(size_t)row * 256 + tid];
    __syncthreads();
#pragma unroll
    for (int off = 1; off < 256; off <<= 1) {
        float t = (tid >= off) ? s[tid - off] : 0.f;
        __syncthreads();
        s[tid] += t;
        __syncthreads();
    }
    float* prow = ii + (size_t)bc * 66049 + (size_t)(y + 1) * 257;
    prow[tid + 1] = s[tid];
    if (tid == 0) prow[0] = 0.f;
}

__global__ void zrow_k(float* __restrict__ ii, int total)
{
    int i = blockIdx.x * 256 + threadIdx.x;
    if (i < total) {
        int bc = i / 257, x = i % 257;
        ii[(size_t)bc * 66049 + x] = 0.f;
    }
}

__global__ __launch_bounds__(256) void colscan_k(float* __restrict__ ii)
{
    float* plane = ii + (size_t)blockIdx.x * 66049;
    const int x = threadIdx.x + 1;
    float acc = 0.f;
    for (int y = 1; y <= 256; ++y) {
        float* p = plane + (size_t)y * 257 + x;
        acc += *p;
        *p = acc;
    }
}

// ---- fused adaptive ROI pool (7x7 via integral image) + FC ----
__global__ __launch_bounds__(512) void roifc_k(
    const float* __restrict__ ii, const int* __restrict__ rois,
    const float* __restrict__ fcw, const float* __restrict__ fcb,
    float* __restrict__ out)
{
    __shared__ float sp[49];
    const int n = blockIdx.x, b = blockIdx.y;
    const int tid = threadIdx.x;
    if (tid < 49) {
        const int i = tid / 7, j = tid % 7;
        int x1, y1, x2, y2, c;
        if (n < 32) {
            x1 = 0; y1 = 0; x2 = 256; y2 = 256; c = n;
        } else {
            int r = (n - 32) >> 5;
            c = (n - 32) & 31;
            x1 = rois[r * 4 + 0]; y1 = rois[r * 4 + 1];
            x2 = rois[r * 4 + 2]; y2 = rois[r * 4 + 3];
        }
        const int h = y2 - y1, w = x2 - x1;
        const int sy = y1 + (i * h) / 7, ey = y1 + ((i + 1) * h + 6) / 7;
        const int sx = x1 + (j * w) / 7, ex = x1 + ((j + 1) * w + 6) / 7;
        const float* pl = ii + (size_t)(b * 32 + c) * 66049;
        float s = pl[ey * 257 + ex] - pl[sy * 257 + ex] - pl[ey * 257 + sx] + pl[sy * 257 + sx];
        sp[tid] = s / (float)((ey - sy) * (ex - sx));
    }
    __syncthreads();
    float a = fcb[tid];
    const float* wr = fcw + (size_t)tid * 49;
#pragma unroll
    for (int k = 0; k < 49; k++) a = fmaf(sp[k], wr[k], a);
    out[((size_t)(b * 1056) + n) * 512 + tid] = a;
}

extern "C" void kernel_launch(void* const* d_in, const int* in_sizes, int n_in,
                              void* d_out, int out_size, void* d_ws, size_t ws_size,
                              hipStream_t stream)
{
    const float* x    = (const float*)d_in[0];
    const int*   rois = (const int*)d_in[1];
    const float* e1w1 = (const float*)d_in[2];
    const float* e1b1 = (const float*)d_in[3];
    const float* e1w2 = (const float*)d_in[4];
    const float* e1b2 = (const float*)d_in[5];
    const float* e2w1 = (const float*)d_in[6];
    const float* e2b1 = (const float*)d_in[7];
    const float* e2w2 = (const float*)d_in[8];
    const float* e2b2 = (const float*)d_in[9];
    const float* bw1  = (const float*)d_in[10];
    const float* bb1  = (const float*)d_in[11];
    const float* bw2  = (const float*)d_in[12];
    const float* bb2  = (const float*)d_in[13];
    const float* u2w  = (const float*)d_in[14];
    const float* u2b  = (const float*)d_in[15];
    const float* d2w1 = (const float*)d_in[16];
    const float* d2b1 = (const float*)d_in[17];
    const float* d2w2 = (const float*)d_in[18];
    const float* d2b2 = (const float*)d_in[19];
    const float* u1w  = (const float*)d_in[20];
    const float* u1b  = (const float*)d_in[21];
    const float* d1w1 = (const float*)d_in[22];
    const float* d1b1 = (const float*)d_in[23];
    const float* d1w2 = (const float*)d_in[24];
    const float* d1b2 = (const float*)d_in[25];
    const float* fw   = (const float*)d_in[26];
    const float* fb   = (const float*)d_in[27];
    const float* fcw  = (const float*)d_in[28];
    const float* fcb  = (const float*)d_in[29];

    // ---- workspace: WT(4MB) A(33.5) D(16.8) E(16.8) B(33.5) C(8.4) F(67.6) = 181 MB
    char* wsb = (char*)d_ws;
    char* WT = wsb;
    char* A  = wsb + 4194304;
    char* D  = A + 33554432;
    char* E  = D + 16777216;
    char* Bb = E + 16777216;
    char* C  = Bb + 33554432;
    char* F  = C + 8388608;
    float* fbuf = (float*)A;   // f spans A+D+E (67,108,864 B exactly)
    float* ii   = (float*)F;

    // ---- weight transforms ----
    const float* wsrc[11] = {e1w2, e2w1, e2w2, bw1, bw2, u2w, d2w1, d2w2, u1w, d1w1, d1w2};
    const int wco[11] = {32, 64, 64, 128, 128, 64, 64, 64, 32, 32, 32};
    const int wci[11] = {32, 32, 64, 64, 128, 128, 128, 64, 64, 64, 32};
    size_t woff[11]; size_t o = 0;
    for (int i = 0; i < 11; ++i) { woff[i] = o; o += (size_t)wco[i] * wci[i] * 18; }
    for (int i = 0; i < 11; ++i) {
        int total = wco[i] * wci[i] * 9;
        hipLaunchKernelGGL(wprep_k, dim3((total + 255) / 256), dim3(256), 0, stream,
                           wsrc[i], (unsigned short*)(WT + woff[i]), wco[i], wci[i], total);
    }

    auto CV = [&](const void* i1, int C1, const void* i2, int C2, int widx,
                  const float* bs, void* ot, int Cout, int H, int lw, int TH,
                  int up, int relu, int BM) {
        dim3 g(1, H / TH, 8 * (Cout / BM));
        const uint4* wp = (const uint4*)(WT + woff[widx]);
        if (BM == 32)
            hipLaunchKernelGGL((convm_k<32>), g, dim3(256), 0, stream,
                               (const uint4*)i1, C1 / 8, (const uint4*)i2, C2 / 8, wp, bs,
                               (unsigned short*)ot, Cout, H, lw, TH, up, relu);
        else
            hipLaunchKernelGGL((convm_k<64>), g, dim3(256), 0, stream,
                               (const uint4*)i1, C1 / 8, (const uint4*)i2, C2 / 8, wp, bs,
                               (unsigned short*)ot, Cout, H, lw, TH, up, relu);
    };

    // encoder
    hipLaunchKernelGGL(conv0_k, dim3(16, 16, 32), dim3(16, 16), 0, stream,
                       x, e1w1, e1b1, (unsigned short*)A);            // e1a -> A
    CV(A, 32, nullptr, 0, 0, e1b2, Bb, 32, 256, 8, 1, 0, 1, 32);     // e1  -> B
    {
        int N = 8 * 128 * 128 * 4;
        hipLaunchKernelGGL(poolh_k, dim3((N + 255) / 256), dim3(256), 0, stream,
                           (const uint4*)Bb, (uint4*)C, 128, 128, 4, N);  // p1 -> C
    }
    CV(C, 32, nullptr, 0, 1, e2b1, A, 64, 128, 7, 2, 0, 1, 64);      // e2a -> A
    CV(A, 64, nullptr, 0, 2, e2b2, D, 64, 128, 7, 2, 0, 1, 64);      // e2  -> D
    {
        int N = 8 * 64 * 64 * 8;
        hipLaunchKernelGGL(poolh_k, dim3((N + 255) / 256), dim3(256), 0, stream,
                           (const uint4*)D, (uint4*)C, 64, 64, 8, N);     // p2 -> C
    }
    // bottleneck
    CV(C, 64, nullptr, 0, 3, bb1, E, 128, 64, 6, 4, 0, 1, 64);       // b1 -> E
    CV(E, 128, nullptr, 0, 4, bb2, A, 128, 64, 6, 4, 0, 1, 64);      // b2 -> A
    // decoder level 2
    CV(A, 128, nullptr, 0, 5, u2b, E, 64, 128, 7, 2, 1, 1, 64);      // u2 -> E (upsample)
    CV(E, 64, D, 64, 6, d2b1, A, 64, 128, 7, 2, 0, 1, 64);           // d2a -> A (concat u2,e2)
    CV(A, 64, nullptr, 0, 7, d2b2, D, 64, 128, 7, 2, 0, 1, 64);      // d2 -> D
    // decoder level 1
    CV(D, 64, nullptr, 0, 8, u1b, A, 32, 256, 8, 1, 1, 1, 32);       // u1 -> A (upsample)
    CV(A, 32, Bb, 32, 9, d1b1, D, 32, 256, 8, 1, 0, 1, 32);          // d1a -> D(+E) (concat u1,e1)
    CV(D, 32, nullptr, 0, 10, d1b2, Bb, 32, 256, 8, 1, 0, 1, 32);    // d1 -> B
    // final 1x1 (fp16 NHWC -> fp32 NCHW planes)
    hipLaunchKernelGGL(conv1x1h_k, dim3(8 * 65536 / 256), dim3(256), 0, stream,
                       (const uint4*)Bb, fw, fb, fbuf);              // f -> A+D+E
    // integral image
    hipLaunchKernelGGL(rowscan_k, dim3(8 * 32 * 256), dim3(256), 0, stream, fbuf, ii);
    hipLaunchKernelGGL(zrow_k, dim3((8 * 32 * 257 + 255) / 256), dim3(256), 0, stream, ii, 8 * 32 * 257);
    hipLaunchKernelGGL(colscan_k, dim3(8 * 32), dim3(256), 0, stream, ii);
    // fused ROI adaptive pool + FC
    hipLaunchKernelGGL(roifc_k, dim3(1056, 8), dim3(512), 0, stream,
                       ii, rois, fcw, fcb, (float*)d_out);
}

// Round 4
// 498.651 us; speedup vs baseline: 7.4938x; 1.3385x over previous
//
#include <hip/hip_runtime.h>

typedef _Float16 half8 __attribute__((ext_vector_type(8)));
typedef float f32x4 __attribute__((ext_vector_type(4)));

__device__ __forceinline__ unsigned short f2h(float f) {
    _Float16 h = (_Float16)f;
    return __builtin_bit_cast(unsigned short, h);
}
__device__ __forceinline__ float h2f(unsigned short u) {
    return (float)__builtin_bit_cast(_Float16, u);
}

// async global->LDS, 16 B per lane; LDS dest must be linear (base + lane*16)
__device__ __forceinline__ void lds_load16(const uint4* g, uint4* l) {
    __builtin_amdgcn_global_load_lds(
        (const __attribute__((address_space(1))) unsigned int*)g,
        (__attribute__((address_space(3))) unsigned int*)l, 16, 0, 0);
}

// ---- weight transform: OIHW fp32 -> [ck][pos][oct(ci/8)][co][ci&7] fp16 ----
__global__ void wprep_k(const float* __restrict__ src, unsigned short* __restrict__ dst,
                        int Cout, int Cin, int total)
{
    int t = blockIdx.x * 256 + threadIdx.x;
    if (t >= total) return;
    int j = t & 7; int r = t >> 3;
    int co = r % Cout; r /= Cout;
    int oct = r & 3; r >>= 2;
    int pos = r % 9; int ck = r / 9;
    int ci = ck * 32 + oct * 8 + j;
    dst[t] = f2h(src[((size_t)co * Cin + ci) * 9 + pos]);
}

// ---- MFMA conv3x3 SAME, NHWC fp16, fp32 accum; 2D tiles, async staging ----
// Block 256 thr = 4 waves; tile TH rows x TW cols; BM out-channels.
// LDS: input [oct(4)][TH+2][TW+2] 16B granules, then weights [pos*4+oct][co].
template<int BM, int TW, int TH, int LW, int UP>
__global__ __launch_bounds__(256, 2) void convm2_k(
    const uint4* __restrict__ in1, int C1g,
    const uint4* __restrict__ in2, int C2g,
    const uint4* __restrict__ wt,
    const float* __restrict__ bias,
    unsigned short* __restrict__ out,
    int Cout, int relu, const uint4* __restrict__ zp)
{
    constexpr int NM = BM / 16;
    constexpr int NN = (TW * TH) / 64;        // 16-px frags per wave
    constexpr int Wf = 1 << LW, Hf = Wf;      // full image dims (square)
    constexpr int WC = TW + 2, HR = TH + 2;
    constexpr int IN_GR = 4 * HR * WC;
    constexpr int LTW = (TW == 64) ? 6 : ((TW == 32) ? 5 : 7);
    constexpr int sH = UP ? (Hf >> 1) : Hf;
    constexpr int sW = UP ? (Wf >> 1) : Wf;
    __shared__ uint4 smem[IN_GR + 36 * BM];

    const int tid = threadIdx.x;
    const int lane = tid & 63, wv = tid >> 6;
    const int ng = Cout / BM;
    const int b = blockIdx.z / ng, cg = blockIdx.z % ng;
    const int x0 = blockIdx.x * TW, y0 = blockIdx.y * TH;
    const int NCK = (C1g + C2g) / 4;

    f32x4 acc[NM][NN];
#pragma unroll
    for (int m = 0; m < NM; ++m)
#pragma unroll
        for (int n = 0; n < NN; ++n) acc[m][n] = (f32x4){0.f, 0.f, 0.f, 0.f};

    const int l15 = lane & 15, l4 = lane >> 4;
    const int laneB = l4 * HR * WC + l15;
    const int laneA = l4 * BM + l15;

    for (int ck = 0; ck < NCK; ++ck) {
        if (ck) __syncthreads();
        // ---- async-stage input chunk (32 ch) with halo; concat src select ----
        {
            const uint4* src; int cg0, srcCg;
            if (ck * 4 < C1g) { src = in1; cg0 = ck * 4; srcCg = C1g; }
            else              { src = in2; cg0 = ck * 4 - C1g; srcCg = C2g; }
            for (int i = tid; i < IN_GR; i += 256) {
                int oct = i / (HR * WC);
                int rem = i - oct * (HR * WC);
                int row = rem / WC;
                int col = rem - row * WC;
                int gy = y0 + row - 1, gx = x0 + col - 1;
                int sy = UP ? (gy >> 1) : gy, sx = UP ? (gx >> 1) : gx;
                const uint4* ga = ((unsigned)gy < (unsigned)Hf && (unsigned)gx < (unsigned)Wf)
                    ? src + ((((size_t)b * sH + sy) * sW + sx) * srcCg + cg0 + oct)
                    : zp + (i & 63);
                lds_load16(ga, &smem[i]);
            }
        }
        // ---- async-stage weight chunk: 36 segs x BM co granules ----
        {
            const uint4* wck = wt + (size_t)ck * 36 * Cout + (size_t)cg * BM;
            for (int i = tid; i < 36 * BM; i += 256) {
                int seg = i / BM, col = i - seg * BM;
                lds_load16(wck + seg * Cout + col, &smem[IN_GR + i]);
            }
        }
        __syncthreads();
        const half8* sB = (const half8*)smem;
        const half8* sA = (const half8*)(smem + IN_GR);
#pragma unroll
        for (int pos = 0; pos < 9; ++pos) {
            const int dr = pos / 3, dc = pos - dr * 3;
            half8 af[NM], bfr[NN];
#pragma unroll
            for (int m = 0; m < NM; ++m)
                af[m] = sA[pos * 4 * BM + m * 16 + laneA];
#pragma unroll
            for (int n = 0; n < NN; ++n) {
                const int pb = wv * (NN * 16) + n * 16;
                const int rn = (pb >> LTW) + dr;
                const int xn = (pb & (TW - 1)) + dc;
                bfr[n] = sB[rn * WC + xn + laneB];
            }
#pragma unroll
            for (int m = 0; m < NM; ++m)
#pragma unroll
                for (int n = 0; n < NN; ++n)
                    acc[m][n] = __builtin_amdgcn_mfma_f32_16x16x32_f16(af[m], bfr[n], acc[m][n], 0, 0, 0);
        }
    }

    // ---- epilogue: bias + relu, pack fp16, NHWC store ----
#pragma unroll
    for (int m = 0; m < NM; ++m) {
        const int co0 = cg * BM + m * 16 + l4 * 4;
        const float4 bs = *(const float4*)(bias + co0);
#pragma unroll
        for (int n = 0; n < NN; ++n) {
            const int pix = wv * (NN * 16) + n * 16 + l15;
            const int y = y0 + (pix >> LTW), x = x0 + (pix & (TW - 1));
            float v0 = acc[m][n][0] + bs.x;
            float v1 = acc[m][n][1] + bs.y;
            float v2 = acc[m][n][2] + bs.z;
            float v3 = acc[m][n][3] + bs.w;
            if (relu) {
                v0 = fmaxf(v0, 0.f); v1 = fmaxf(v1, 0.f);
                v2 = fmaxf(v2, 0.f); v3 = fmaxf(v3, 0.f);
            }
            uint2 pk;
            pk.x = (unsigned)f2h(v0) | ((unsigned)f2h(v1) << 16);
            pk.y = (unsigned)f2h(v2) | ((unsigned)f2h(v3) << 16);
            *(uint2*)(out + (((size_t)b * Hf + y) * Wf + x) * Cout + co0) = pk;
        }
    }
}

// ---- first conv 3->32, fp32 direct, NCHW fp32 in -> NHWC fp16 out ----
__global__ __launch_bounds__(256) void conv0_k(
    const float* __restrict__ in, const float* __restrict__ w,
    const float* __restrict__ bias, unsigned short* __restrict__ out)
{
    __shared__ float s_in[3][18][18];
    const int tx = threadIdx.x, ty = threadIdx.y;
    const int tid = ty * 16 + tx;
    const int b = blockIdx.z >> 2;
    const int coBase = (blockIdx.z & 3) * 8;
    const int bx = blockIdx.x * 16, by = blockIdx.y * 16;

    for (int i = tid; i < 3 * 18 * 18; i += 256) {
        int cc = i / 324, r = i % 324;
        int ly = r / 18, lx = r % 18;
        int gy = by + ly - 1, gx = bx + lx - 1;
        float v = 0.f;
        if ((unsigned)gy < 256u && (unsigned)gx < 256u)
            v = in[(((size_t)(b * 3 + cc)) << 16) + (gy << 8) + gx];
        ((float*)s_in)[i] = v;
    }
    __syncthreads();
    float acc[8];
#pragma unroll
    for (int k = 0; k < 8; ++k) acc[k] = 0.f;
    for (int cc = 0; cc < 3; ++cc) {
        float v[9];
#pragma unroll
        for (int dh = 0; dh < 3; ++dh)
#pragma unroll
            for (int dw = 0; dw < 3; ++dw)
                v[dh * 3 + dw] = s_in[cc][ty + dh][tx + dw];
        const float* wp = w + ((size_t)coBase * 3 + cc) * 9;
#pragma unroll
        for (int k = 0; k < 8; ++k) {
            const float* wk = wp + (size_t)k * 27;
            float a = acc[k];
#pragma unroll
            for (int j = 0; j < 9; ++j) a = fmaf(v[j], wk[j], a);
            acc[k] = a;
        }
    }
    const int h = by + ty, ww = bx + tx;
    unsigned short* op = out + (((size_t)(b * 256 + h)) * 256 + ww) * 32 + coBase;
#pragma unroll
    for (int k = 0; k < 8; ++k)
        op[k] = f2h(fmaxf(acc[k] + bias[coBase + k], 0.f));
}

// ---- 2x2 maxpool stride 2, NHWC fp16, 8 ch per thread ----
__global__ void poolh_k(const uint4* __restrict__ in, uint4* __restrict__ out,
                        int Ho, int Wo, int C8, int total)
{
    int i = blockIdx.x * 256 + threadIdx.x;
    if (i >= total) return;
    int oct = i % C8; int p = i / C8;
    int x = p % Wo; p /= Wo;
    int y = p % Ho; int b = p / Ho;
    const int H = Ho * 2, W = Wo * 2;
    size_t g = (((size_t)b * H + 2 * y) * W + 2 * x) * C8 + oct;
    uint4 v00 = in[g], v01 = in[g + C8];
    uint4 v10 = in[g + (size_t)W * C8], v11 = in[g + (size_t)W * C8 + C8];
    const unsigned short* a0 = (const unsigned short*)&v00;
    const unsigned short* a1 = (const unsigned short*)&v01;
    const unsigned short* a2 = (const unsigned short*)&v10;
    const unsigned short* a3 = (const unsigned short*)&v11;
    uint4 res; unsigned short* rp = (unsigned short*)&res;
#pragma unroll
    for (int j = 0; j < 8; ++j)
        rp[j] = f2h(fmaxf(fmaxf(h2f(a0[j]), h2f(a1[j])), fmaxf(h2f(a2[j]), h2f(a3[j]))));
    out[(((size_t)b * Ho + y) * Wo + x) * C8 + oct] = res;
}

// ---- 1x1 conv 32->32, NHWC fp16 in -> NCHW fp32 out ----
__global__ __launch_bounds__(256) void conv1x1h_k(
    const uint4* __restrict__ in, const float* __restrict__ w,
    const float* __restrict__ bias, float* __restrict__ out)
{
    __shared__ float sw[1024];
    __shared__ float sb[32];
    const int tid = threadIdx.x;
    for (int i = tid; i < 1024; i += 256) sw[i] = w[i];
    if (tid < 32) sb[tid] = bias[tid];
    __syncthreads();
    const size_t p = (size_t)blockIdx.x * 256 + tid;
    float xv[32];
    const uint4* ip = in + p * 4;
#pragma unroll
    for (int q = 0; q < 4; ++q) {
        uint4 g = ip[q];
        const unsigned short* gs = (const unsigned short*)&g;
#pragma unroll
        for (int j = 0; j < 8; ++j) xv[q * 8 + j] = h2f(gs[j]);
    }
    const int b = (int)(p >> 16);
    const int pix = (int)(p & 65535);
    float* op = out + (((size_t)b * 32) << 16) + pix;
#pragma unroll
    for (int co = 0; co < 32; ++co) {
        float a = sb[co];
#pragma unroll
        for (int ci = 0; ci < 32; ++ci) a = fmaf(xv[ci], sw[co * 32 + ci], a);
        op[(size_t)co << 16] = a;
    }
}

// ---- integral image: row inclusive scan ----
__global__ __launch_bounds__(256) void rowscan_k(const float* __restrict__ f,
                                                 float* __restrict__ ii)
{
    __shared__ float s[256];
    const int row = blockIdx.x;
    const int tid = threadIdx.x;
    const int bc = row >> 8, y = row & 255;
    s[tid] = f[(size_t)row * 256 + tid];
    __syncthreads();
#pragma unroll
    for (int off = 1; off < 256; off <<= 1) {
        float t = (tid >= off) ? s[tid - off] : 0.f;
        __syncthreads();
        s[tid] += t;
        __syncthreads();
    }
    float* prow = ii + (size_t)bc * 66049 + (size_t)(y + 1) * 257;
    prow[tid + 1] = s[tid];
    if (tid == 0) prow[0] = 0.f;
}

__global__ void zrow_k(float* __restrict__ ii, int total)
{
    int i = blockIdx.x * 256 + threadIdx.x;
    if (i < total) {
        int bc = i / 257, x = i % 257;
        ii[(size_t)bc * 66049 + x] = 0.f;
    }
}

__global__ __launch_bounds__(256) void colscan_k(float* __restrict__ ii)
{
    float* plane = ii + (size_t)blockIdx.x * 66049;
    const int x = threadIdx.x + 1;
    float acc = 0.f;
    for (int y = 1; y <= 256; ++y) {
        float* p = plane + (size_t)y * 257 + x;
        acc += *p;
        *p = acc;
    }
}

// ---- fused adaptive ROI pool (7x7 via integral image) + FC ----
__global__ __launch_bounds__(512) void roifc_k(
    const float* __restrict__ ii, const int* __restrict__ rois,
    const float* __restrict__ fcw, const float* __restrict__ fcb,
    float* __restrict__ out)
{
    __shared__ float sp[49];
    const int n = blockIdx.x, b = blockIdx.y;
    const int tid = threadIdx.x;
    if (tid < 49) {
        const int i = tid / 7, j = tid % 7;
        int x1, y1, x2, y2, c;
        if (n < 32) {
            x1 = 0; y1 = 0; x2 = 256; y2 = 256; c = n;
        } else {
            int r = (n - 32) >> 5;
            c = (n - 32) & 31;
            x1 = rois[r * 4 + 0]; y1 = rois[r * 4 + 1];
            x2 = rois[r * 4 + 2]; y2 = rois[r * 4 + 3];
        }
        const int h = y2 - y1, w = x2 - x1;
        const int sy = y1 + (i * h) / 7, ey = y1 + ((i + 1) * h + 6) / 7;
        const int sx = x1 + (j * w) / 7, ex = x1 + ((j + 1) * w + 6) / 7;
        const float* pl = ii + (size_t)(b * 32 + c) * 66049;
        float s = pl[ey * 257 + ex] - pl[sy * 257 + ex] - pl[ey * 257 + sx] + pl[sy * 257 + sx];
        sp[tid] = s / (float)((ey - sy) * (ex - sx));
    }
    __syncthreads();
    float a = fcb[tid];
    const float* wr = fcw + (size_t)tid * 49;
#pragma unroll
    for (int k = 0; k < 49; k++) a = fmaf(sp[k], wr[k], a);
    out[((size_t)(b * 1056) + n) * 512 + tid] = a;
}

extern "C" void kernel_launch(void* const* d_in, const int* in_sizes, int n_in,
                              void* d_out, int out_size, void* d_ws, size_t ws_size,
                              hipStream_t stream)
{
    const float* x    = (const float*)d_in[0];
    const int*   rois = (const int*)d_in[1];
    const float* e1w1 = (const float*)d_in[2];
    const float* e1b1 = (const float*)d_in[3];
    const float* e1w2 = (const float*)d_in[4];
    const float* e1b2 = (const float*)d_in[5];
    const float* e2w1 = (const float*)d_in[6];
    const float* e2b1 = (const float*)d_in[7];
    const float* e2w2 = (const float*)d_in[8];
    const float* e2b2 = (const float*)d_in[9];
    const float* bw1  = (const float*)d_in[10];
    const float* bb1  = (const float*)d_in[11];
    const float* bw2  = (const float*)d_in[12];
    const float* bb2  = (const float*)d_in[13];
    const float* u2w  = (const float*)d_in[14];
    const float* u2b  = (const float*)d_in[15];
    const float* d2w1 = (const float*)d_in[16];
    const float* d2b1 = (const float*)d_in[17];
    const float* d2w2 = (const float*)d_in[18];
    const float* d2b2 = (const float*)d_in[19];
    const float* u1w  = (const float*)d_in[20];
    const float* u1b  = (const float*)d_in[21];
    const float* d1w1 = (const float*)d_in[22];
    const float* d1b1 = (const float*)d_in[23];
    const float* d1w2 = (const float*)d_in[24];
    const float* d1b2 = (const float*)d_in[25];
    const float* fw   = (const float*)d_in[26];
    const float* fb   = (const float*)d_in[27];
    const float* fcw  = (const float*)d_in[28];
    const float* fcb  = (const float*)d_in[29];

    // ---- workspace: WT(4MB incl zero-page) A(33.5) D(16.8) E(16.8) B(33.5) C(8.4) F(67.6)
    char* wsb = (char*)d_ws;
    char* WT = wsb;
    char* A  = wsb + 4194304;
    char* D  = A + 33554432;
    char* E  = D + 16777216;
    char* Bb = E + 16777216;
    char* C  = Bb + 33554432;
    char* F  = C + 8388608;
    float* fbuf = (float*)A;   // f spans A+D+E
    float* ii   = (float*)F;
    uint4* zp   = (uint4*)(wsb + 4194304 - 8192);  // zero page for OOB staging
    hipMemsetAsync(zp, 0, 8192, stream);

    // ---- weight transforms ----
    const float* wsrc[11] = {e1w2, e2w1, e2w2, bw1, bw2, u2w, d2w1, d2w2, u1w, d1w1, d1w2};
    const int wco[11] = {32, 64, 64, 128, 128, 64, 64, 64, 32, 32, 32};
    const int wci[11] = {32, 32, 64, 64, 128, 128, 128, 64, 64, 64, 32};
    size_t woff[11]; size_t o = 0;
    for (int i = 0; i < 11; ++i) { woff[i] = o; o += (size_t)wco[i] * wci[i] * 18; }
    for (int i = 0; i < 11; ++i) {
        int total = wco[i] * wci[i] * 9;
        hipLaunchKernelGGL(wprep_k, dim3((total + 255) / 256), dim3(256), 0, stream,
                           wsrc[i], (unsigned short*)(WT + woff[i]), wco[i], wci[i], total);
    }
    auto WP = [&](int i) { return (const uint4*)(WT + woff[i]); };

    // geometry: 256²: BM32 TW64 TH8 LW8 -> grid(4,32,8*ng)
    //           128²: BM64 TW64 TH8 LW7 -> grid(2,16,8)
    //            64²: BM64 TW64 TH4 LW6 -> grid(1,16,8*ng)
    #define CV1(i1,C1,i2,C2,wi,bs,ot,Cout,up,rl) \
        hipLaunchKernelGGL((convm2_k<32,64,8,8,up>), dim3(4,32,8*((Cout)/32)), dim3(256), 0, stream, \
            (const uint4*)(i1), (C1)/8, (const uint4*)(i2), (C2)/8, WP(wi), bs, \
            (unsigned short*)(ot), Cout, rl, zp)
    #define CV2(i1,C1,i2,C2,wi,bs,ot,Cout,up,rl) \
        hipLaunchKernelGGL((convm2_k<64,64,8,7,up>), dim3(2,16,8*((Cout)/64)), dim3(256), 0, stream, \
            (const uint4*)(i1), (C1)/8, (const uint4*)(i2), (C2)/8, WP(wi), bs, \
            (unsigned short*)(ot), Cout, rl, zp)
    #define CV3(i1,C1,i2,C2,wi,bs,ot,Cout,up,rl) \
        hipLaunchKernelGGL((convm2_k<64,64,4,6,up>), dim3(1,16,8*((Cout)/64)), dim3(256), 0, stream, \
            (const uint4*)(i1), (C1)/8, (const uint4*)(i2), (C2)/8, WP(wi), bs, \
            (unsigned short*)(ot), Cout, rl, zp)

    // encoder
    hipLaunchKernelGGL(conv0_k, dim3(16, 16, 32), dim3(16, 16), 0, stream,
                       x, e1w1, e1b1, (unsigned short*)A);        // e1a -> A
    CV1(A, 32, nullptr, 0, 0, e1b2, Bb, 32, 0, 1);               // e1  -> B
    {
        int N = 8 * 128 * 128 * 4;
        hipLaunchKernelGGL(poolh_k, dim3((N + 255) / 256), dim3(256), 0, stream,
                           (const uint4*)Bb, (uint4*)C, 128, 128, 4, N);  // p1 -> C
    }
    CV2(C, 32, nullptr, 0, 1, e2b1, A, 64, 0, 1);                // e2a -> A
    CV2(A, 64, nullptr, 0, 2, e2b2, D, 64, 0, 1);                // e2  -> D
    {
        int N = 8 * 64 * 64 * 8;
        hipLaunchKernelGGL(poolh_k, dim3((N + 255) / 256), dim3(256), 0, stream,
                           (const uint4*)D, (uint4*)C, 64, 64, 8, N);     // p2 -> C
    }
    // bottleneck
    CV3(C, 64, nullptr, 0, 3, bb1, E, 128, 0, 1);                // b1 -> E
    CV3(E, 128, nullptr, 0, 4, bb2, A, 128, 0, 1);               // b2 -> A
    // decoder level 2
    CV2(A, 128, nullptr, 0, 5, u2b, E, 64, 1, 1);                // u2 -> E (upsample)
    CV2(E, 64, D, 64, 6, d2b1, A, 64, 0, 1);                     // d2a -> A (concat)
    CV2(A, 64, nullptr, 0, 7, d2b2, D, 64, 0, 1);                // d2 -> D
    // decoder level 1
    CV1(D, 64, nullptr, 0, 8, u1b, A, 32, 1, 1);                 // u1 -> A (upsample)
    CV1(A, 32, Bb, 32, 9, d1b1, D, 32, 0, 1);                    // d1a -> D (concat)
    CV1(D, 32, nullptr, 0, 10, d1b2, Bb, 32, 0, 1);              // d1 -> B
    // final 1x1
    hipLaunchKernelGGL(conv1x1h_k, dim3(8 * 65536 / 256), dim3(256), 0, stream,
                       (const uint4*)Bb, fw, fb, fbuf);          // f -> A+D+E
    // integral image
    hipLaunchKernelGGL(rowscan_k, dim3(8 * 32 * 256), dim3(256), 0, stream, fbuf, ii);
    hipLaunchKernelGGL(zrow_k, dim3((8 * 32 * 257 + 255) / 256), dim3(256), 0, stream, ii, 8 * 32 * 257);
    hipLaunchKernelGGL(colscan_k, dim3(8 * 32), dim3(256), 0, stream, ii);
    // fused ROI adaptive pool + FC
    hipLaunchKernelGGL(roifc_k, dim3(1056, 8), dim3(512), 0, stream,
                       ii, rois, fcw, fcb, (float*)d_out);
    #undef CV1
    #undef CV2
    #undef CV3
}